// Round 16
// baseline (195.387 us; speedup 1.0000x reference)
//
#include <hip/hip_runtime.h>

// GCN: 2x GraphConv(128->128, norm='both') + ReLU, then Linear(128->16).
// N=100000, E=600000, D=128, C=16.
//
// Round 16: intra-block work stealing for the fused gather kernels.
// r15's g1g2 pinned 8 serial nodes per 32-lane group -> block duration =
// max over groups (imbalance) and concurrency decays at the block barrier
// (achieved occupancy 30%). Now groups draw rows from an LDS atomic pool
// (balance = sum/8 + tail). Also: counter zeroing folded into wpack
// (one fewer dispatch).

typedef __attribute__((ext_vector_type(4))) _Float16 half4_t;
typedef __attribute__((ext_vector_type(16))) float floatx16;

// exclusive scan of cnt_in -> starts; also emits rs_out/rs_in (fused)
__global__ __launch_bounds__(256) void scan1_kernel(
    const int* __restrict__ cntI, const int* __restrict__ cntO,
    int* __restrict__ excl, int* __restrict__ bsum,
    float* __restrict__ rs_out, float* __restrict__ rs_in, int n)
{
    __shared__ int tmp[256];
    int i = blockIdx.x * 256 + threadIdx.x;
    int v = 0;
    if (i < n) {
        v = cntI[i];
        rs_in[i]  = rsqrtf(fmaxf((float)v, 1.0f));
        rs_out[i] = rsqrtf(fmaxf((float)cntO[i], 1.0f));
    }
    tmp[threadIdx.x] = v;
    __syncthreads();
    for (int off = 1; off < 256; off <<= 1) {
        int t = (threadIdx.x >= off) ? tmp[threadIdx.x - off] : 0;
        __syncthreads();
        tmp[threadIdx.x] += t;
        __syncthreads();
    }
    if (i < n) excl[i] = tmp[threadIdx.x] - v;
    if (threadIdx.x == 255) bsum[blockIdx.x] = tmp[255];
}

__global__ __launch_bounds__(1024) void scan2_kernel(int* __restrict__ bsum, int nb)
{
    __shared__ int tmp[1024];
    int t = threadIdx.x;
    int v = (t < nb) ? bsum[t] : 0;
    tmp[t] = v;
    __syncthreads();
    for (int off = 1; off < 1024; off <<= 1) {
        int x = (t >= off) ? tmp[t - off] : 0;
        __syncthreads();
        tmp[t] += x;
        __syncthreads();
    }
    if (t < nb) bsum[t] = tmp[t] - v;   // exclusive
}

__global__ __launch_bounds__(256) void scan3_kernel(
    int* __restrict__ excl, const int* __restrict__ bsum, int n)
{
    int i = blockIdx.x * 256 + threadIdx.x;
    if (i < n) excl[i] += bsum[blockIdx.x];
}

// atomic-free fill: slot precomputed from starts + per-edge rank
__global__ __launch_bounds__(256) void fill_kernel(
    const int* __restrict__ src, const int* __restrict__ dst,
    const int* __restrict__ rank, const int* __restrict__ starts,
    int* __restrict__ eidx, int E)
{
    int e = blockIdx.x * blockDim.x + threadIdx.x;
    if (e < E) {
        eidx[starts[dst[e]] + rank[e]] = src[e];
    }
}

// Pack W (fp32 [k][col]) into frag-major f16 + zero the degree counters
// (zeroing folded here: sequential dispatch order guarantees completion
// before fused1's atomics).
__global__ __launch_bounds__(256) void wpack_kernel(
    const float* __restrict__ W1, const float* __restrict__ W2,
    _Float16* __restrict__ WB1, _Float16* __restrict__ WB2,
    int* __restrict__ cnt, int n2)
{
    int gid = blockIdx.x * 256 + threadIdx.x;      // 0..32767
    for (int i = gid; i < n2; i += 32768) cnt[i] = 0;
    int j = gid & 16383;
    int i   = j & 3;
    int col = (j >> 2) & 127;
    int g   = (j >> 9) & 1;
    int kt  = j >> 10;
    int k = kt * 8 + g * 4 + i;
    if (gid < 16384) WB1[j] = (_Float16)W1[k * 128 + col];
    else             WB2[j] = (_Float16)W2[k * 128 + col];
}

// MFMA main loop + T write for a 64-row tile whose A is already staged
// (swizzled) in xa. Wave (rhalf,chalf): rows rhalf*32+[0,32), cols
// chalf*64+[0,64). B from frag-major WB (global, L2-hot).
__device__ __forceinline__ void mfma_and_store(
    char* xab, int bid, const _Float16* __restrict__ WB,
    _Float16* __restrict__ T, int n)
{
    const int tid  = threadIdx.x;
    const int lane = tid & 63;
    const int wv   = tid >> 6;
    const int m    = lane & 31;
    const int g    = lane >> 5;
    const int rhalf = wv & 1;
    const int chalf = wv >> 1;
    const int rbase = bid * 64 + rhalf * 32;

    floatx16 acc0 = {}, acc1 = {};
    const int arow = rhalf * 32 + m;
    const _Float16* wb = WB + (size_t)(g * 128 + chalf * 64 + m) * 4;

#pragma unroll 2
    for (int kt = 0; kt < 16; ++kt) {
        int cbyte = kt * 16 + g * 8;
        half4_t a = *(const half4_t*)(xab + ((arow * 256 + cbyte) ^ ((m & 7) << 4)));
        const _Float16* wk = wb + (size_t)kt * 1024;
        half4_t b0 = *(const half4_t*)(wk);
        half4_t b1 = *(const half4_t*)(wk + 128);   // +32 cols
        acc0 = __builtin_amdgcn_mfma_f32_32x32x8f16(a, b0, acc0, 0, 0, 0);
        acc1 = __builtin_amdgcn_mfma_f32_32x32x8f16(a, b1, acc1, 0, 0, 0);
    }

#pragma unroll
    for (int rg = 0; rg < 16; ++rg) {
        int rd = (rg & 3) + 8 * (rg >> 2) + 4 * g;
        int orow = rbase + rd;
        if (orow < n) {
            _Float16* tp = T + (size_t)orow * 128 + chalf * 64 + m;
            tp[0]  = (_Float16)acc0[rg];
            tp[32] = (_Float16)acc1[rg];
        }
    }
}

// One 64-row GEMM tile staged from global X (fp32, no scale) -> T f16.
__device__ __forceinline__ void gemm_tile64_f32in(
    int bid, const float* __restrict__ X, const _Float16* __restrict__ WB,
    _Float16* __restrict__ T, int n)
{
    __shared__ _Float16 xa[64 * 128];   // 16 KB
    char* xab = (char*)xa;
    const int tid = threadIdx.x;
    {
        const int C = (tid & 31) * 4;
        const int rsub = tid >> 5;
#pragma unroll
        for (int p = 0; p < 8; ++p) {
            int R = p * 8 + rsub;
            int row = bid * 64 + R;
            half4_t a;
            if (row < n) {
                float4 v = *(const float4*)&X[(size_t)row * 128 + C];
                a[0] = (_Float16)v.x;
                a[1] = (_Float16)v.y;
                a[2] = (_Float16)v.z;
                a[3] = (_Float16)v.w;
            } else {
                a[0] = a[1] = a[2] = a[3] = (_Float16)0.f;
            }
            int byte = (R * 256 + C * 2) ^ ((R & 7) << 4);
            *(half4_t*)(xab + byte) = a;
        }
    }
    __syncthreads();
    mfma_and_store(xab, bid, WB, T, n);
}

// fused1: interleaved count + layer-1 GEMM (16 KB LDS).
__global__ __launch_bounds__(256) void fused1_kernel(
    const float* __restrict__ h, const _Float16* __restrict__ WB1,
    _Float16* __restrict__ T1,
    const int* __restrict__ src, const int* __restrict__ dst,
    int* __restrict__ cntO, int* __restrict__ cntI, int* __restrict__ rank,
    int n, int E, int GB, int S)
{
    int bid = blockIdx.x;
    int g = bid / S, r = bid - g * S;
    if (r == 0 && g < GB) {
        gemm_tile64_f32in(g, h, WB1, T1, n);
    } else {
        int ng = g + (r ? 1 : 0);            // gemm blocks with id < bid
        if (ng > GB) ng = GB;
        int cb = bid - ng;                   // contiguous count-block index
        int t = cb * 256 + threadIdx.x;
        if (t < E) {
            atomicAdd(&cntO[src[t]], 1);           // fire-and-forget
        } else if (t < 2 * E) {
            int e = t - E;
            rank[e] = atomicAdd(&cntI[dst[e]], 1); // returning (rank)
        }
    }
}

// shared edge-accumulation, 8-edge unroll (32-lane group, lane t: half4)
template <int PES>
__device__ __forceinline__ void edge_accum(
    const _Float16* __restrict__ T, const int* __restrict__ eidx,
    const float* __restrict__ rs_out, int s0, int s1, int t, float acc[4])
{
    int j = s0;
    for (; j + 7 < s1; j += 8) {
        int4 sA = *(const int4*)&eidx[j];
        int4 sB = *(const int4*)&eidx[j + 4];
        half4_t v0 = *(const half4_t*)&T[(size_t)sA.x * 128 + t * 4];
        half4_t v1 = *(const half4_t*)&T[(size_t)sA.y * 128 + t * 4];
        half4_t v2 = *(const half4_t*)&T[(size_t)sA.z * 128 + t * 4];
        half4_t v3 = *(const half4_t*)&T[(size_t)sA.w * 128 + t * 4];
        half4_t v4 = *(const half4_t*)&T[(size_t)sB.x * 128 + t * 4];
        half4_t v5 = *(const half4_t*)&T[(size_t)sB.y * 128 + t * 4];
        half4_t v6 = *(const half4_t*)&T[(size_t)sB.z * 128 + t * 4];
        half4_t v7 = *(const half4_t*)&T[(size_t)sB.w * 128 + t * 4];
        if (PES) {
            float r0 = rs_out[sA.x], r1 = rs_out[sA.y];
            float r2 = rs_out[sA.z], r3 = rs_out[sA.w];
            float r4 = rs_out[sB.x], r5 = rs_out[sB.y];
            float r6 = rs_out[sB.z], r7 = rs_out[sB.w];
#pragma unroll
            for (int i = 0; i < 4; ++i) {
                acc[i] = fmaf((float)v0[i], r0, acc[i]);
                acc[i] = fmaf((float)v1[i], r1, acc[i]);
                acc[i] = fmaf((float)v2[i], r2, acc[i]);
                acc[i] = fmaf((float)v3[i], r3, acc[i]);
                acc[i] = fmaf((float)v4[i], r4, acc[i]);
                acc[i] = fmaf((float)v5[i], r5, acc[i]);
                acc[i] = fmaf((float)v6[i], r6, acc[i]);
                acc[i] = fmaf((float)v7[i], r7, acc[i]);
            }
        } else {
#pragma unroll
            for (int i = 0; i < 4; ++i) {
                float s01 = (float)v0[i] + (float)v1[i];
                float s23 = (float)v2[i] + (float)v3[i];
                float s45 = (float)v4[i] + (float)v5[i];
                float s67 = (float)v6[i] + (float)v7[i];
                acc[i] += (s01 + s23) + (s45 + s67);
            }
        }
    }
    if (j + 3 < s1) {
        int4 sA = *(const int4*)&eidx[j];
        half4_t v0 = *(const half4_t*)&T[(size_t)sA.x * 128 + t * 4];
        half4_t v1 = *(const half4_t*)&T[(size_t)sA.y * 128 + t * 4];
        half4_t v2 = *(const half4_t*)&T[(size_t)sA.z * 128 + t * 4];
        half4_t v3 = *(const half4_t*)&T[(size_t)sA.w * 128 + t * 4];
        if (PES) {
            float r0 = rs_out[sA.x], r1 = rs_out[sA.y];
            float r2 = rs_out[sA.z], r3 = rs_out[sA.w];
#pragma unroll
            for (int i = 0; i < 4; ++i) {
                acc[i] = fmaf((float)v0[i], r0, acc[i]);
                acc[i] = fmaf((float)v1[i], r1, acc[i]);
                acc[i] = fmaf((float)v2[i], r2, acc[i]);
                acc[i] = fmaf((float)v3[i], r3, acc[i]);
            }
        } else {
#pragma unroll
            for (int i = 0; i < 4; ++i)
                acc[i] += ((float)v0[i] + (float)v1[i]) + ((float)v2[i] + (float)v3[i]);
        }
        j += 4;
    }
    for (; j < s1; ++j) {
        int sA = eidx[j];
        half4_t va = *(const half4_t*)&T[(size_t)sA * 128 + t * 4];
        float ra = PES ? rs_out[sA] : 1.0f;
#pragma unroll
        for (int i = 0; i < 4; ++i) acc[i] = fmaf((float)va[i], ra, acc[i]);
    }
}

// g1g2: gather layer-1 for 64 nodes into the swizzled LDS A-tile, then MFMA
// with WB2 -> T2. Groups draw rows from an LDS atomic pool (work stealing:
// block duration ~ sum/8 + tail instead of max over fixed 8-node chains).
__global__ __launch_bounds__(256) void g1g2_kernel(
    const _Float16* __restrict__ T1, const int* __restrict__ eidx,
    const int* __restrict__ starts, const float* __restrict__ rs_in,
    const float* __restrict__ rs_out, const float* __restrict__ bias,
    const _Float16* __restrict__ WB2, _Float16* __restrict__ T2, int n, int E)
{
    __shared__ _Float16 xa[64 * 128];   // 16 KB
    __shared__ int pool;
    char* xab = (char*)xa;
    const int tid = threadIdx.x;
    if (tid == 0) pool = 0;
    __syncthreads();
    const int t   = tid & 31;
    const int bid = blockIdx.x;

    for (;;) {
        int r = 0;
        if (t == 0) r = atomicAdd(&pool, 1);
        r = __shfl(r, 0, 32);
        if (r >= 64) break;
        int node = bid * 64 + r;
        half4_t o;
        if (node < n) {
            int s0 = starts[node];
            int s1 = (node + 1 < n) ? starts[node + 1] : E;
            float acc[4] = {0.f, 0.f, 0.f, 0.f};
            edge_accum<1>(T1, eidx, rs_out, s0, s1, t, acc);
            float ri = rs_in[node];
            float ro = rs_out[node];
            float4 bv = *(const float4*)&bias[t * 4];
            float bb[4] = {bv.x, bv.y, bv.z, bv.w};
#pragma unroll
            for (int i = 0; i < 4; ++i)
                o[i] = (_Float16)(fmaxf(fmaf(acc[i], ri, bb[i]), 0.f) * ro);
        } else {
            o[0] = o[1] = o[2] = o[3] = (_Float16)0.f;
        }
        int byte = (r * 256 + t * 8) ^ ((r & 7) << 4);
        *(half4_t*)(xab + byte) = o;
    }
    __syncthreads();
    mfma_and_store(xab, bid, WB2, T2, n);
}

// g2cls: gather layer-2 for 16 nodes into the classifier LDS tile (pool-
// assigned), then out[node][:] = relu(agg*rs_in + b2) @ Wc + bc.
// Conflict-free wl[k*16+c].
__global__ __launch_bounds__(256) void g2cls_kernel(
    const _Float16* __restrict__ T2, const int* __restrict__ eidx,
    const int* __restrict__ starts, const float* __restrict__ rs_in,
    const float* __restrict__ bias, const float* __restrict__ Wc,
    const float* __restrict__ bout, float* __restrict__ outp, int n, int E)
{
    __shared__ float wl[128 * 16];       // 8 KB
    __shared__ _Float16 xs[16][128];     // 4 KB
    __shared__ int pool;
    const int tid = threadIdx.x;
    const int row0 = blockIdx.x * 16;
    if (tid == 0) pool = 0;
#pragma unroll
    for (int i0 = 0; i0 < 2; ++i0) {
        int i = tid + i0 * 256;
        ((float4*)wl)[i] = ((const float4*)Wc)[i];
    }
    __syncthreads();

    const int t = tid & 31;
    for (;;) {
        int r = 0;
        if (t == 0) r = atomicAdd(&pool, 1);
        r = __shfl(r, 0, 32);
        if (r >= 16) break;
        int node = row0 + r;
        half4_t o;
        if (node < n) {
            int s0 = starts[node];
            int s1 = (node + 1 < n) ? starts[node + 1] : E;
            float acc[4] = {0.f, 0.f, 0.f, 0.f};
            edge_accum<0>(T2, eidx, nullptr, s0, s1, t, acc);
            float ri = rs_in[node];
            float4 bv = *(const float4*)&bias[t * 4];
            float bb[4] = {bv.x, bv.y, bv.z, bv.w};
#pragma unroll
            for (int i = 0; i < 4; ++i)
                o[i] = (_Float16)fmaxf(fmaf(acc[i], ri, bb[i]), 0.f);
        } else {
            o[0] = o[1] = o[2] = o[3] = (_Float16)0.f;
        }
        *(half4_t*)&xs[r][t * 4] = o;
    }
    __syncthreads();

    int c = tid & 15, r = tid >> 4;
    float acc = 0.f;
#pragma unroll 4
    for (int k = 0; k < 128; k += 2) {
        float x0 = (float)xs[r][k];
        float x1 = (float)xs[r][k + 1];
        acc = fmaf(x0, wl[k * 16 + c], acc);
        acc = fmaf(x1, wl[(k + 1) * 16 + c], acc);
    }
    int row = row0 + r;
    if (row < n) outp[(size_t)row * 16 + c] = acc + bout[c];
}

extern "C" void kernel_launch(void* const* d_in, const int* in_sizes, int n_in,
                              void* d_out, int out_size, void* d_ws, size_t ws_size,
                              hipStream_t stream)
{
    const float* h   = (const float*)d_in[0];
    const int*   src = (const int*)d_in[1];
    const int*   dst = (const int*)d_in[2];
    const float* W1  = (const float*)d_in[3];
    const float* b1  = (const float*)d_in[4];
    const float* W2  = (const float*)d_in[5];
    const float* b2  = (const float*)d_in[6];
    const float* Wc  = (const float*)d_in[7];
    const float* bc  = (const float*)d_in[8];
    float* out = (float*)d_out;

    const int n = in_sizes[0] / 128;   // 100000
    const int E = in_sizes[1];         // 600000
    const int nb = (n + 255) / 256;    // 391 (<=1024)

    char* ws = (char*)d_ws;
    int*   cntO    = (int*)ws;                       // n
    int*   cntI    = cntO + n;                       // n
    int*   rank    = cntI + n;                       // E
    float* rs_out  = (float*)(rank + E);             // n
    float* rs_in   = rs_out + n;                     // n
    int*   starts  = (int*)(rs_in + n);              // n
    int*   bsum    = starts + n;                     // 1024
    int*   eidx    = bsum + 1024;                    // E
    _Float16* WB1  = (_Float16*)(eidx + E);          // 16384
    _Float16* WB2  = WB1 + 16384;                    // 16384
    size_t off = ((size_t)((char*)(WB2 + 16384) - ws) + 255) & ~(size_t)255;
    _Float16* bufA = (_Float16*)(ws + off);          // n*128 f16 (T1)
    _Float16* bufB = bufA + (size_t)n * 128;         // n*128 f16 (T2)

    const int CB = (2 * E + 255) / 256;   // count blocks (4688)
    const int GB = (n + 63) / 64;         // gemm/g1g2 blocks (1563)
    const int S  = (CB + GB) / GB;        // interleave stride (3)

    // weight pack + counter zeroing (one dispatch)
    wpack_kernel<<<128, 256, 0, stream>>>(W1, W2, WB1, WB2, cntO, 2 * n);
    // count + layer-1 GEMM fused, block-interleaved, 16 KB LDS
    fused1_kernel<<<CB + GB, 256, 0, stream>>>(h, WB1, bufA, src, dst,
                                               cntO, cntI, rank, n, E, GB, S);
    scan1_kernel<<<nb, 256, 0, stream>>>(cntI, cntO, starts, bsum, rs_out, rs_in, n);
    scan2_kernel<<<1, 1024, 0, stream>>>(bsum, nb);
    scan3_kernel<<<nb, 256, 0, stream>>>(starts, bsum, n);
    fill_kernel<<<(E + 255) / 256, 256, 0, stream>>>(src, dst, rank, starts, eidx, E);

    // gather1 + gemm2 fused (X2 lives only in LDS); T1=bufA -> T2=bufB
    g1g2_kernel<<<GB, 256, 0, stream>>>(bufA, eidx, starts, rs_in, rs_out,
                                        b1, WB2, bufB, n, E);

    // gather2 + classifier fused (X3 lives only in LDS); T2=bufB -> out
    g2cls_kernel<<<(n + 15) / 16, 256, 0, stream>>>(bufB, eidx, starts, rs_in,
                                                    b2, Wc, bc, out, n, E);
}

// Round 17
// 185.350 us; speedup vs baseline: 1.0542x; 1.0542x over previous
//
#include <hip/hip_runtime.h>

// GCN: 2x GraphConv(128->128, norm='both') + ReLU, then Linear(128->16).
// N=100000, E=600000, D=128, C=16.
//
// Round 17: revert to the measured-best r12 configuration (191.1us):
// split gather/gemm/classifier kernels, 4-edge gather unroll (r14's 8-edge
// regressed), fused1 {count | gemm1} with 64-row 16KB-LDS tiles. Keep one
// r16 trim: degree-counter zeroing folded into wpack (one fewer dispatch).
//
// Established floors (probed multiple directions, r5-r16):
//  - count: device atomic service ~22-25 ops/ns -> ~48-55us, hidden under gemm1
//  - gather: L3 random 256B-row service ~3.4-3.8 TB/s -> ~40-45us each
//  - gemm2/classifier: HBM-bound at byte counts

typedef __attribute__((ext_vector_type(4))) _Float16 half4_t;
typedef __attribute__((ext_vector_type(16))) float floatx16;

// exclusive scan of cnt_in -> starts; also emits rs_out/rs_in (fused)
__global__ __launch_bounds__(256) void scan1_kernel(
    const int* __restrict__ cntI, const int* __restrict__ cntO,
    int* __restrict__ excl, int* __restrict__ bsum,
    float* __restrict__ rs_out, float* __restrict__ rs_in, int n)
{
    __shared__ int tmp[256];
    int i = blockIdx.x * 256 + threadIdx.x;
    int v = 0;
    if (i < n) {
        v = cntI[i];
        rs_in[i]  = rsqrtf(fmaxf((float)v, 1.0f));
        rs_out[i] = rsqrtf(fmaxf((float)cntO[i], 1.0f));
    }
    tmp[threadIdx.x] = v;
    __syncthreads();
    for (int off = 1; off < 256; off <<= 1) {
        int t = (threadIdx.x >= off) ? tmp[threadIdx.x - off] : 0;
        __syncthreads();
        tmp[threadIdx.x] += t;
        __syncthreads();
    }
    if (i < n) excl[i] = tmp[threadIdx.x] - v;
    if (threadIdx.x == 255) bsum[blockIdx.x] = tmp[255];
}

__global__ __launch_bounds__(1024) void scan2_kernel(int* __restrict__ bsum, int nb)
{
    __shared__ int tmp[1024];
    int t = threadIdx.x;
    int v = (t < nb) ? bsum[t] : 0;
    tmp[t] = v;
    __syncthreads();
    for (int off = 1; off < 1024; off <<= 1) {
        int x = (t >= off) ? tmp[t - off] : 0;
        __syncthreads();
        tmp[t] += x;
        __syncthreads();
    }
    if (t < nb) bsum[t] = tmp[t] - v;   // exclusive
}

__global__ __launch_bounds__(256) void scan3_kernel(
    int* __restrict__ excl, const int* __restrict__ bsum, int n)
{
    int i = blockIdx.x * 256 + threadIdx.x;
    if (i < n) excl[i] += bsum[blockIdx.x];
}

// atomic-free fill: slot precomputed from starts + per-edge rank
__global__ __launch_bounds__(256) void fill_kernel(
    const int* __restrict__ src, const int* __restrict__ dst,
    const int* __restrict__ rank, const int* __restrict__ starts,
    int* __restrict__ eidx, int E)
{
    int e = blockIdx.x * blockDim.x + threadIdx.x;
    if (e < E) {
        eidx[starts[dst[e]] + rank[e]] = src[e];
    }
}

// Pack W (fp32 [k][col]) into frag-major f16 + zero degree counters
// (sequential dispatch order guarantees completion before fused1).
__global__ __launch_bounds__(256) void wpack_kernel(
    const float* __restrict__ W1, const float* __restrict__ W2,
    _Float16* __restrict__ WB1, _Float16* __restrict__ WB2,
    int* __restrict__ cnt, int n2)
{
    int gid = blockIdx.x * 256 + threadIdx.x;      // 0..32767
    for (int i = gid; i < n2; i += 32768) cnt[i] = 0;
    int j = gid & 16383;
    int i   = j & 3;
    int col = (j >> 2) & 127;
    int g   = (j >> 9) & 1;
    int kt  = j >> 10;
    int k = kt * 8 + g * 4 + i;
    if (gid < 16384) WB1[j] = (_Float16)W1[k * 128 + col];
    else             WB2[j] = (_Float16)W2[k * 128 + col];
}

// One 64-row GEMM tile: T[bid*64 .. +64][0..128) = X @ W, f16 out.
// A staged in XOR-swizzled 16 KB LDS; B from frag-major WB (global, L2-hot).
// MODE 0: X fp32 (cast, no scale).  MODE 1: X f16.
template <int MODE>
__device__ __forceinline__ void gemm_tile64(
    int bid, const void* __restrict__ Xv, const _Float16* __restrict__ WB,
    _Float16* __restrict__ T, int n)
{
    __shared__ _Float16 xa[64 * 128];   // 16 KB
    char* xab = (char*)xa;

    const int tid  = threadIdx.x;
    const int lane = tid & 63;
    const int wv   = tid >> 6;
    const int m    = lane & 31;
    const int g    = lane >> 5;
    const int rhalf = wv & 1;
    const int chalf = wv >> 1;
    const int rbase = bid * 64 + rhalf * 32;

    // ---- stage A: rows [bid*64, +64), coalesced global reads ----
    {
        const int C = (tid & 31) * 4;          // half4 column
        const int rsub = tid >> 5;             // 8 rows per pass
#pragma unroll
        for (int p = 0; p < 8; ++p) {
            int R = p * 8 + rsub;
            int row = bid * 64 + R;
            half4_t a;
            if (row < n) {
                if (MODE == 0) {
                    const float* X = (const float*)Xv;
                    float4 v = *(const float4*)&X[(size_t)row * 128 + C];
                    a[0] = (_Float16)v.x;
                    a[1] = (_Float16)v.y;
                    a[2] = (_Float16)v.z;
                    a[3] = (_Float16)v.w;
                } else {
                    const _Float16* X = (const _Float16*)Xv;
                    a = *(const half4_t*)&X[(size_t)row * 128 + C];
                }
            } else {
                a[0] = a[1] = a[2] = a[3] = (_Float16)0.f;
            }
            int byte = (R * 256 + C * 2) ^ ((R & 7) << 4);
            *(half4_t*)(xab + byte) = a;
        }
    }
    __syncthreads();

    // ---- MFMA main loop (2 col-tiles per wave) ----
    floatx16 acc0 = {}, acc1 = {};
    const int arow = rhalf * 32 + m;
    const _Float16* wb = WB + (size_t)(g * 128 + chalf * 64 + m) * 4;

#pragma unroll 2
    for (int kt = 0; kt < 16; ++kt) {
        int cbyte = kt * 16 + g * 8;
        half4_t a = *(const half4_t*)(xab + ((arow * 256 + cbyte) ^ ((m & 7) << 4)));
        const _Float16* wk = wb + (size_t)kt * 1024;
        half4_t b0 = *(const half4_t*)(wk);
        half4_t b1 = *(const half4_t*)(wk + 128);   // +32 cols
        acc0 = __builtin_amdgcn_mfma_f32_32x32x8f16(a, b0, acc0, 0, 0, 0);
        acc1 = __builtin_amdgcn_mfma_f32_32x32x8f16(a, b1, acc1, 0, 0, 0);
    }

#pragma unroll
    for (int rg = 0; rg < 16; ++rg) {
        int rd = (rg & 3) + 8 * (rg >> 2) + 4 * g;
        int orow = rbase + rd;
        if (orow < n) {
            _Float16* tp = T + (size_t)orow * 128 + chalf * 64 + m;
            tp[0]  = (_Float16)acc0[rg];
            tp[32] = (_Float16)acc1[rg];
        }
    }
}

// fused1: interleaved count + layer-1 GEMM (16 KB LDS -> count blocks get
// 8 blocks/CU). gemm tile k at bid=k*S; count blocks fill the gaps.
__global__ __launch_bounds__(256) void fused1_kernel(
    const float* __restrict__ h, const _Float16* __restrict__ WB1,
    _Float16* __restrict__ T1,
    const int* __restrict__ src, const int* __restrict__ dst,
    int* __restrict__ cntO, int* __restrict__ cntI, int* __restrict__ rank,
    int n, int E, int GB, int S)
{
    int bid = blockIdx.x;
    int g = bid / S, r = bid - g * S;
    if (r == 0 && g < GB) {
        gemm_tile64<0>(g, h, WB1, T1, n);
    } else {
        int ng = g + (r ? 1 : 0);            // gemm blocks with id < bid
        if (ng > GB) ng = GB;
        int cb = bid - ng;                   // contiguous count-block index
        int t = cb * 256 + threadIdx.x;
        if (t < E) {
            atomicAdd(&cntO[src[t]], 1);           // fire-and-forget
        } else if (t < 2 * E) {
            int e = t - E;
            rank[e] = atomicAdd(&cntI[dst[e]], 1); // returning (rank)
        }
    }
}

__global__ __launch_bounds__(256) void gemm2_kernel(
    const _Float16* __restrict__ X, const _Float16* __restrict__ WB,
    _Float16* __restrict__ T, int n)
{
    gemm_tile64<1>(blockIdx.x, X, WB, T, n);
}

// shared edge-accumulation: 32-lane group, lane t holds halves [t*4,t*4+4),
// 4-edge unroll (r12 form; r14's 8-edge regressed).
template <int PES>
__device__ __forceinline__ void edge_accum(
    const _Float16* __restrict__ T, const int* __restrict__ eidx,
    const float* __restrict__ rs_out, int s0, int s1, int t, float acc[4])
{
    int j = s0;
    for (; j + 3 < s1; j += 4) {
        int4 s4 = *(const int4*)&eidx[j];
        half4_t va = *(const half4_t*)&T[(size_t)s4.x * 128 + t * 4];
        half4_t vb = *(const half4_t*)&T[(size_t)s4.y * 128 + t * 4];
        half4_t vc = *(const half4_t*)&T[(size_t)s4.z * 128 + t * 4];
        half4_t vd = *(const half4_t*)&T[(size_t)s4.w * 128 + t * 4];
        if (PES) {
            float ra = rs_out[s4.x], rb = rs_out[s4.y];
            float rc = rs_out[s4.z], rd = rs_out[s4.w];
#pragma unroll
            for (int i = 0; i < 4; ++i) {
                acc[i] = fmaf((float)va[i], ra, acc[i]);
                acc[i] = fmaf((float)vb[i], rb, acc[i]);
                acc[i] = fmaf((float)vc[i], rc, acc[i]);
                acc[i] = fmaf((float)vd[i], rd, acc[i]);
            }
        } else {
#pragma unroll
            for (int i = 0; i < 4; ++i)
                acc[i] += ((float)va[i] + (float)vb[i]) + ((float)vc[i] + (float)vd[i]);
        }
    }
    for (; j < s1; ++j) {
        int sA = eidx[j];
        half4_t va = *(const half4_t*)&T[(size_t)sA * 128 + t * 4];
        float ra = PES ? rs_out[sA] : 1.0f;
#pragma unroll
        for (int i = 0; i < 4; ++i) acc[i] = fmaf((float)va[i], ra, acc[i]);
    }
}

// gather: Xout = f16(relu((sum scale*T[s]) * rs_in + b) [* rs_out]).
// 2 nodes/wave, 32-lane group per node, half4/lane (coalesced 256 B row txn).
// PES: per-edge rs_out[s] scaling (layer 1; T1 is unscaled h@W1).
// NS: epilogue *rs_out[node] (layer 1 output feeds layer 2's GEMM).
template <int PES, int NS>
__global__ __launch_bounds__(256) void gather_f16(
    const _Float16* __restrict__ T, const int* __restrict__ eidx,
    const int* __restrict__ starts, const float* __restrict__ rs_in,
    const float* __restrict__ rs_out, const float* __restrict__ bias,
    _Float16* __restrict__ Xout, int n, int E)
{
    int wave = (blockIdx.x * 256 + threadIdx.x) >> 6;
    int lane = threadIdx.x & 63;
    int q = lane >> 5;
    int t = lane & 31;
    int node = wave * 2 + q;
    if (node >= n) return;
    int s0 = starts[node];
    int s1 = (node + 1 < n) ? starts[node + 1] : E;

    float acc[4] = {0.f, 0.f, 0.f, 0.f};
    edge_accum<PES>(T, eidx, rs_out, s0, s1, t, acc);

    float ri = rs_in[node];
    float ro = NS ? rs_out[node] : 1.0f;
    float4 bv = *(const float4*)&bias[t * 4];
    float bb[4] = {bv.x, bv.y, bv.z, bv.w};
    half4_t o;
#pragma unroll
    for (int i = 0; i < 4; ++i) {
        float x = fmaxf(fmaf(acc[i], ri, bb[i]), 0.f) * ro;
        o[i] = (_Float16)x;
    }
    *(half4_t*)&Xout[(size_t)node * 128 + t * 4] = o;
}

// out[n,16] = X3 @ Wc + bc  (X3 f16, relu/bias already applied).
// wl[k*16+c]: 16 lanes read 16 consecutive floats -> 16 distinct banks,
// conflict-free.
__global__ __launch_bounds__(256) void classifier_kernel(
    const _Float16* __restrict__ X, const float* __restrict__ Wc,
    const float* __restrict__ bout, float* __restrict__ out, int n)
{
    __shared__ float wl[128 * 16];       // 8 KB
    __shared__ _Float16 xs[16][128];     // 4 KB
    const int tid = threadIdx.x;
    const int row0 = blockIdx.x * 16;
#pragma unroll
    for (int i0 = 0; i0 < 2; ++i0) {
        int i = tid + i0 * 256;
        ((float4*)wl)[i] = ((const float4*)Wc)[i];
    }
    {
        int r = tid >> 4, c8 = (tid & 15) * 8;
        int row = row0 + r;
        float4 v = make_float4(0.f, 0.f, 0.f, 0.f);
        if (row < n) v = *(const float4*)&X[(size_t)row * 128 + c8];
        *(float4*)&xs[r][c8] = v;
    }
    __syncthreads();
    int c = tid & 15, r = tid >> 4;
    float acc = 0.f;
#pragma unroll 4
    for (int k = 0; k < 128; k += 2) {
        float x0 = (float)xs[r][k];
        float x1 = (float)xs[r][k + 1];
        acc = fmaf(x0, wl[k * 16 + c], acc);
        acc = fmaf(x1, wl[(k + 1) * 16 + c], acc);
    }
    int row = row0 + r;
    if (row < n) out[(size_t)row * 16 + c] = acc + bout[c];
}

extern "C" void kernel_launch(void* const* d_in, const int* in_sizes, int n_in,
                              void* d_out, int out_size, void* d_ws, size_t ws_size,
                              hipStream_t stream)
{
    const float* h   = (const float*)d_in[0];
    const int*   src = (const int*)d_in[1];
    const int*   dst = (const int*)d_in[2];
    const float* W1  = (const float*)d_in[3];
    const float* b1  = (const float*)d_in[4];
    const float* W2  = (const float*)d_in[5];
    const float* b2  = (const float*)d_in[6];
    const float* Wc  = (const float*)d_in[7];
    const float* bc  = (const float*)d_in[8];
    float* out = (float*)d_out;

    const int n = in_sizes[0] / 128;   // 100000
    const int E = in_sizes[1];         // 600000
    const int nb = (n + 255) / 256;    // 391 (<=1024)

    char* ws = (char*)d_ws;
    int*   cntO    = (int*)ws;                       // n
    int*   cntI    = cntO + n;                       // n
    int*   rank    = cntI + n;                       // E
    float* rs_out  = (float*)(rank + E);             // n
    float* rs_in   = rs_out + n;                     // n
    int*   starts  = (int*)(rs_in + n);              // n
    int*   bsum    = starts + n;                     // 1024
    int*   eidx    = bsum + 1024;                    // E
    _Float16* WB1  = (_Float16*)(eidx + E);          // 16384
    _Float16* WB2  = WB1 + 16384;                    // 16384
    size_t off = ((size_t)((char*)(WB2 + 16384) - ws) + 255) & ~(size_t)255;
    _Float16* bufA = (_Float16*)(ws + off);          // n*128 f16
    _Float16* bufB = bufA + (size_t)n * 128;         // n*128 f16

    const int CB = (2 * E + 255) / 256;   // count blocks (4688)
    const int GB = (n + 63) / 64;         // gemm blocks (1563, 64-row tiles)
    const int S  = (CB + GB) / GB;        // interleave stride (3)

    // weight pack + counter zeroing (one dispatch)
    wpack_kernel<<<128, 256, 0, stream>>>(W1, W2, WB1, WB2, cntO, 2 * n);
    // count + layer-1 GEMM fused, block-interleaved, 16 KB LDS
    fused1_kernel<<<CB + GB, 256, 0, stream>>>(h, WB1, bufA, src, dst,
                                               cntO, cntI, rank, n, E, GB, S);
    scan1_kernel<<<nb, 256, 0, stream>>>(cntI, cntO, starts, bsum, rs_out, rs_in, n);
    scan2_kernel<<<1, 1024, 0, stream>>>(bsum, nb);
    scan3_kernel<<<nb, 256, 0, stream>>>(starts, bsum, n);
    fill_kernel<<<(E + 255) / 256, 256, 0, stream>>>(src, dst, rank, starts, eidx, E);

    int ablocks = (n + 7) / 8;       // gather: 4 waves/block x 2 nodes/wave

    // Layer 1 aggregate (per-edge rs_out scaling; epilogue feeds layer 2)
    gather_f16<1, 1><<<ablocks, 256, 0, stream>>>(bufA, eidx, starts, rs_in, rs_out, b1, bufB, n, E);

    // Layer 2 GEMM
    gemm2_kernel<<<GB, 256, 0, stream>>>(bufB, WB2, bufA, n);

    // Layer 2 aggregate
    gather_f16<0, 0><<<ablocks, 256, 0, stream>>>(bufA, eidx, starts, rs_in, rs_out, b2, bufB, n, E);

    // Classifier
    classifier_kernel<<<(n + 15) / 16, 256, 0, stream>>>(bufB, Wc, bc, out, n);
}